// Round 8
// baseline (321.664 us; speedup 1.0000x reference)
//
#include <hip/hip_runtime.h>
#include <stdint.h>

typedef unsigned short u16;
typedef __bf16 bf16x8 __attribute__((ext_vector_type(8)));
typedef float f32x4 __attribute__((ext_vector_type(4)));
typedef __attribute__((address_space(1))) const unsigned int as1_u32;
typedef __attribute__((address_space(3))) unsigned int as3_u32;

#define SEQ 4096
#define HID 1152
#define NH 16
#define HD 72

__device__ __forceinline__ void gload_lds16(const void* g, void* l) {
  __builtin_amdgcn_global_load_lds((as1_u32*)g, (as3_u32*)l, 16, 0, 0);
}
__device__ __forceinline__ u16 f2bf(float f) {
  __bf16 h = (__bf16)f;
  return __builtin_bit_cast(u16, h);
}
__device__ __forceinline__ float bf2f(u16 u) {
  unsigned int x = ((unsigned int)u) << 16;
  return __builtin_bit_cast(float, x);
}

// ---------------- cast X fp32 -> bf16 ----------------
__global__ void cvt_x(const float* __restrict__ X, u16* __restrict__ Xb, int n4) {
  int i = blockIdx.x * blockDim.x + threadIdx.x;
  if (i < n4) {
    float4 v = *(const float4*)(X + (size_t)i * 4);
    unsigned int lo = f2bf(v.x) | ((unsigned int)f2bf(v.y) << 16);
    unsigned int hi = f2bf(v.z) | ((unsigned int)f2bf(v.w) << 16);
    *(uint2*)(Xb + (size_t)i * 4) = make_uint2(lo, hi);
  }
}

// ---------------- transpose + cast W (1152x1152 each) ----------------
__global__ void transpose_w(const float* __restrict__ Wq, const float* __restrict__ Wk,
                            const float* __restrict__ Wv, const float* __restrict__ Wo,
                            u16* __restrict__ Wt, u16* __restrict__ Wot) {
  __shared__ __align__(16) float t[32][33];
  int z = blockIdx.z;
  const float* src = (z == 0) ? Wq : (z == 1) ? Wk : (z == 2) ? Wv : Wo;
  u16* dst = (z < 3) ? (Wt + (size_t)z * HID * HID) : Wot;
  int tx = threadIdx.x & 31, ty = threadIdx.x >> 5;  // 32 x 8
  int c0 = blockIdx.x * 32, r0 = blockIdx.y * 32;
#pragma unroll
  for (int i = 0; i < 4; i++)
    t[ty + i * 8][tx] = src[(size_t)(r0 + ty + i * 8) * HID + c0 + tx];
  __syncthreads();
#pragma unroll
  for (int i = 0; i < 4; i++)
    dst[(size_t)(c0 + ty + i * 8) * HID + r0 + tx] = f2bf(t[tx][ty + i * 8]);
}

// ---------------- bf16 GEMM  C[M][N] = A[M][K] * Bt[N][K]^T ----------------
template <int OUTBF16>
__global__ __launch_bounds__(256, 2) void gemm_bt(const u16* __restrict__ A,
                                                  const u16* __restrict__ Bt,
                                                  void* __restrict__ Cout,
                                                  int M, int N, int K) {
  __shared__ __align__(16) u16 lds[2][2][128 * 64];
  const int tid = threadIdx.x;
  const int wave = tid >> 6, lane = tid & 63;
  const int l15 = lane & 15, l4 = lane >> 4;
  const size_t bm = (size_t)blockIdx.x * 128, bn = (size_t)blockIdx.y * 128;
  const int wm = (wave >> 1) * 64, wn = (wave & 1) * 64;
  const int nt = K >> 6;

  f32x4 acc[4][4] = {};

  auto stage = [&](int buf, int kt) {
    const int k0 = kt << 6;
#pragma unroll
    for (int r = 0; r < 4; r++) {
      int idx = (r << 8) + tid;
      int m = idx >> 3, j = idx & 7;
      int js = j ^ (m & 7);
      void* ldsA = (void*)&lds[buf][0][(size_t)((r << 8) + (wave << 6)) * 8];
      void* ldsB = (void*)&lds[buf][1][(size_t)((r << 8) + (wave << 6)) * 8];
      gload_lds16(A + (bm + m) * (size_t)K + k0 + js * 8, ldsA);
      gload_lds16(Bt + (bn + m) * (size_t)K + k0 + js * 8, ldsB);
    }
  };

  stage(0, 0);
  for (int t = 0; t < nt; t++) {
    __syncthreads();
    if (t + 1 < nt) stage((t + 1) & 1, t + 1);
    const u16* As = &lds[t & 1][0][0];
    const u16* Bs = &lds[t & 1][1][0];
#pragma unroll
    for (int kk = 0; kk < 2; kk++) {
      bf16x8 af[4], bfr[4];
      int slot = (kk << 2) + l4;
#pragma unroll
      for (int mi = 0; mi < 4; mi++) {
        int m = wm + (mi << 4) + l15;
        af[mi] = *(const bf16x8*)&As[m * 64 + ((slot ^ (m & 7)) << 3)];
      }
#pragma unroll
      for (int ni = 0; ni < 4; ni++) {
        int n = wn + (ni << 4) + l15;
        bfr[ni] = *(const bf16x8*)&Bs[n * 64 + ((slot ^ (n & 7)) << 3)];
      }
#pragma unroll
      for (int mi = 0; mi < 4; mi++)
#pragma unroll
        for (int ni = 0; ni < 4; ni++)
          acc[mi][ni] = __builtin_amdgcn_mfma_f32_16x16x32_bf16(af[mi], bfr[ni], acc[mi][ni], 0, 0, 0);
    }
  }

#pragma unroll
  for (int mi = 0; mi < 4; mi++)
#pragma unroll
    for (int ni = 0; ni < 4; ni++)
#pragma unroll
      for (int r = 0; r < 4; r++) {
        size_t m = bm + wm + (mi << 4) + (l4 << 2) + r;
        size_t n = bn + wn + (ni << 4) + l15;
        if (OUTBF16)
          ((u16*)Cout)[m * N + n] = f2bf(acc[mi][ni][r]);
        else
          ((float*)Cout)[m * N + n] = acc[mi][ni][r];
      }
}

// ---------------- fused RMSNorm + 2D RoPE (tiled, coalesced) ----------------
// C1 bf16 [4096][3456] -> Qp bf16 [h][n][96]  (pad 72..95 = 0),
//                         Kp bf16 [h][n][128] (granules 0..11 written; 12..15 unread pad),
//                         Vt bf16 [h][80][4096] (pad rows 72..79 = 0)
__global__ __launch_bounds__(256, 2) void norm_rope(
    const u16* __restrict__ C1, const float* __restrict__ cosv,
    const float* __restrict__ sinv, const float* __restrict__ qsc,
    const float* __restrict__ ksc, u16* __restrict__ Qp, u16* __restrict__ Kp,
    u16* __restrict__ Vt) {
  __shared__ __align__(16) u16 in_t[32 * 224];
  __shared__ __align__(16) u16 qo[32 * 96];
  __shared__ __align__(16) u16 ko[32 * 96];
  __shared__ __align__(16) u16 vo[80 * 48];
  const int tid = threadIdx.x;
  const int h = blockIdx.y;
  const int n0 = blockIdx.x * 32;

  // phase 1: cooperative load of the 32x216 tile (16B granules)
#pragma unroll
  for (int k = 0; k < 4; k++) {
    int g = tid + k * 256;
    if (g < 864) {
      int row = g / 27, j = g - row * 27;
      int seg = j / 9, c = (j - seg * 9) * 8;
      const u16* src = C1 + (size_t)(n0 + row) * 3456 + seg * 1152 + h * HD + c;
      *(uint4*)&in_t[row * 224 + j * 8] = *(const uint4*)src;
    }
  }
  __syncthreads();

  // phase 2: per-row (8 lanes/row) rms + rope + v-transpose
  const int r = tid >> 3, p = tid & 7;
  float sq = 0, sk = 0, sv = 0;
  auto acc8 = [&](int off, float& s) {
    uint4 v = *(const uint4*)&in_t[r * 224 + off];
    unsigned int vv[4] = {v.x, v.y, v.z, v.w};
#pragma unroll
    for (int q = 0; q < 4; q++) {
      float a = bf2f((u16)(vv[q] & 0xffff));
      float b = bf2f((u16)(vv[q] >> 16));
      s += a * a + b * b;
    }
  };
  acc8(0 + p * 8, sq);
  acc8(72 + p * 8, sk);
  acc8(144 + p * 8, sv);
  if (p == 0) { acc8(64, sq); acc8(136, sk); acc8(208, sv); }
#pragma unroll
  for (int m = 1; m < 8; m <<= 1) {
    sq += __shfl_xor(sq, m);
    sk += __shfl_xor(sk, m);
    sv += __shfl_xor(sv, m);
  }
  const float rq = rsqrtf(sq * (1.0f / 72.0f) + 1e-6f);
  const float rk = rsqrtf(sk * (1.0f / 72.0f) + 1e-6f);
  const float rv = rsqrtf(sv * (1.0f / 72.0f) + 1e-6f);

#pragma unroll
  for (int u = 0; u < 5; u++) {
    int ti = p + (u << 3);
    if (ti < 36) {
      int i1 = ti + ((ti >= 18) ? 18 : 0);
      int i2 = i1 + 18;
      const float* cb = cosv + (size_t)(n0 + r) * HD;
      const float* sb = sinv + (size_t)(n0 + r) * HD;
      float c1 = cb[i1], c2 = cb[i2], s1 = sb[i1], s2 = sb[i2];
      float q1 = bf2f(in_t[r * 224 + i1]) * rq * qsc[i1];
      float q2 = bf2f(in_t[r * 224 + i2]) * rq * qsc[i2];
      float k1 = bf2f(in_t[r * 224 + 72 + i1]) * rk * ksc[i1];
      float k2 = bf2f(in_t[r * 224 + 72 + i2]) * rk * ksc[i2];
      qo[r * 96 + i1] = f2bf(q1 * c1 - q2 * s1);
      qo[r * 96 + i2] = f2bf(q2 * c2 + q1 * s2);
      ko[r * 96 + i1] = f2bf(k1 * c1 - k2 * s1);
      ko[r * 96 + i2] = f2bf(k2 * c2 + k1 * s2);
    }
  }
#pragma unroll
  for (int u = 0; u < 9; u++) {
    int d = p * 9 + u;
    vo[d * 48 + r] = f2bf(bf2f(in_t[r * 224 + 144 + d]) * rv);
  }
  // zero pads: qo/ko granules 9..11 (cols 72..95)
  if (p < 3) {
    uint4 z = make_uint4(0, 0, 0, 0);
    *(uint4*)&qo[r * 96 + (9 + p) * 8] = z;
    *(uint4*)&ko[r * 96 + (9 + p) * 8] = z;
  }
  // zero pads: vo rows 72..79
  if (tid < 32) {
    int d = 72 + (tid >> 2), g = tid & 3;
    *(uint4*)&vo[d * 48 + g * 8] = make_uint4(0, 0, 0, 0);
  }
  __syncthreads();

  // phase 3: coalesced stores (32 rows x 12 granules = 384)
#pragma unroll
  for (int k = 0; k < 2; k++) {
    int g = tid + k * 256;
    if (g < 384) {
      int row = g / 12, j = g - row * 12;
      *(uint4*)(Qp + ((size_t)h * SEQ + n0 + row) * 96 + j * 8) = *(const uint4*)&qo[row * 96 + j * 8];
      *(uint4*)(Kp + ((size_t)h * SEQ + n0 + row) * 128 + j * 8) = *(const uint4*)&ko[row * 96 + j * 8];
    }
  }
#pragma unroll
  for (int k = 0; k < 2; k++) {
    int g = tid + k * 256;
    if (g < 320) {
      int d = g >> 2, j = g & 3;
      *(uint4*)(Vt + ((size_t)h * 80 + d) * SEQ + n0 + j * 8) = *(const uint4*)&vo[d * 48 + j * 8];
    }
  }
}

// ---------------- flash attention ----------------
// 256 threads = 4 waves x 32 q-rows (QBLK=128): halves LDS bytes per unit work vs
// 8x16 (every wave reads the full K/V tile; K-frag reuse doubles). 64-key tiles,
// dbuf, 1 barrier/tile. Q [h][n][96]; K [h][n][128] XOR-swizzled; V [h][80][n].
// Head->XCD clustered block remap. Exact THR=0 defer-max (skip rescale when
// running max didn't grow -> scl==1; round-6 __expf numerics preserved).
__global__ __launch_bounds__(256, 2) void attn(const u16* __restrict__ Qp,
                                               const u16* __restrict__ Kp,
                                               const u16* __restrict__ Vt,
                                               u16* __restrict__ AO) {
  __shared__ __align__(16) u16 Ks[2][64 * 128];  // 32 KB
  __shared__ __align__(16) u16 Vs[2][80 * 64];   // 20 KB
  __shared__ __align__(16) u16 Ps[4][32 * 64];   // 16 KB (per-wave P, 32 q-rows)
  const int tid = threadIdx.x;
  const int wave = tid >> 6, lane = tid & 63;
  const int l15 = lane & 15, l4 = lane >> 4;

  // head->XCD clustering: XCD = linear_bid % 8; each head entirely on one XCD
  const int bid = blockIdx.x + (blockIdx.y << 5);
  const int h = ((bid & 7) << 1) | ((bid >> 3) & 1);
  const int qt = bid >> 4;  // 0..31
  const int q0 = qt * 128 + wave * 32;

  // Q fragments (B-operand: col q = l15, k-slice = kk*32 + l4*8)
  bf16x8 bq[2][3];
#pragma unroll
  for (int qf = 0; qf < 2; qf++) {
    const u16* qbase = Qp + ((size_t)h * SEQ + q0 + (qf << 4) + l15) * 96;
#pragma unroll
    for (int kk = 0; kk < 3; kk++) bq[qf][kk] = *(const bf16x8*)(qbase + kk * 32 + l4 * 8);
  }

  f32x4 acc[2][5] = {};
  float mi_[2] = {-1e30f, -1e30f};
  float li_[2] = {0.0f, 0.0f};

  auto stage = [&](int buf, int k0) {
    // K: 64 rows x 16 granules = 1024, source-swizzled (j ^ row&15), linear LDS dest
#pragma unroll
    for (int i = 0; i < 4; i++) {
      int g = tid + (i << 8);
      int m = g >> 4, j = g & 15;
      int js = j ^ (m & 15);
      gload_lds16(Kp + ((size_t)h * SEQ + k0 + m) * 128 + js * 8,
                  (void*)&Ks[buf][(size_t)((i << 8) + (wave << 6)) * 8]);
    }
    // V: 80 rows x 8 granules = 640, source-swizzled (j ^ d&7)
#pragma unroll
    for (int i = 0; i < 2; i++) {
      int g = tid + (i << 8);
      int d = g >> 3, j = g & 7;
      int js = j ^ (d & 7);
      gload_lds16(Vt + ((size_t)h * 80 + d) * SEQ + k0 + js * 8,
                  (void*)&Vs[buf][(size_t)((i << 8) + (wave << 6)) * 8]);
    }
    if (wave < 2) {
      int g = tid + 512;
      int d = g >> 3, j = g & 7;
      int js = j ^ (d & 7);
      gload_lds16(Vt + ((size_t)h * 80 + d) * SEQ + k0 + js * 8,
                  (void*)&Vs[buf][(size_t)(512 + (wave << 6)) * 8]);
    }
  };

  stage(0, 0);
  for (int t = 0; t < 64; t++) {
    __syncthreads();  // tile t staged (vmcnt drained); buf t+1 free
    if (t < 63) stage((t + 1) & 1, (t + 1) * 64);
    const u16* Kb = Ks[t & 1];
    const u16* Vb = Vs[t & 1];

    // S^T = K * Q  (col q = l15 within qf, row k = nf*16 + l4*4 + r)
    f32x4 s[2][4] = {};
    __builtin_amdgcn_s_setprio(1);
#pragma unroll
    for (int kk = 0; kk < 3; kk++) {
      int slot = (kk << 2) + l4;
      bf16x8 ak[4];
#pragma unroll
      for (int nf = 0; nf < 4; nf++) {
        int row = (nf << 4) + l15;
        ak[nf] = *(const bf16x8*)&Kb[row * 128 + ((slot ^ l15) << 3)];
      }
#pragma unroll
      for (int nf = 0; nf < 4; nf++) {
        s[0][nf] = __builtin_amdgcn_mfma_f32_16x16x32_bf16(ak[nf], bq[0][kk], s[0][nf], 0, 0, 0);
        s[1][nf] = __builtin_amdgcn_mfma_f32_16x16x32_bf16(ak[nf], bq[1][kk], s[1][nf], 0, 0, 0);
      }
    }
    __builtin_amdgcn_s_setprio(0);

    // online softmax per q-frag
#pragma unroll
    for (int qf = 0; qf < 2; qf++) {
      float v0 = fmaxf(fmaxf(s[qf][0][0], s[qf][0][1]), fmaxf(s[qf][0][2], s[qf][0][3]));
      float v1 = fmaxf(fmaxf(s[qf][1][0], s[qf][1][1]), fmaxf(s[qf][1][2], s[qf][1][3]));
      float v2 = fmaxf(fmaxf(s[qf][2][0], s[qf][2][1]), fmaxf(s[qf][2][2], s[qf][2][3]));
      float v3 = fmaxf(fmaxf(s[qf][3][0], s[qf][3][1]), fmaxf(s[qf][3][2], s[qf][3][3]));
      float v = fmaxf(fmaxf(v0, v1), fmaxf(v2, v3));
      v = fmaxf(v, __shfl_xor(v, 16));
      v = fmaxf(v, __shfl_xor(v, 32));
      // exact defer: if max didn't grow, scl == 1 -> skip rescale entirely
      if (!__all(v <= mi_[qf])) {
        float mnew = fmaxf(mi_[qf], v);
        float scl = __expf(mi_[qf] - mnew);
        mi_[qf] = mnew;
        li_[qf] *= scl;
#pragma unroll
        for (int r = 0; r < 4; r++) {
          float sr = __shfl(scl, (l4 << 2) + r);
#pragma unroll
          for (int ni = 0; ni < 5; ni++) acc[qf][ni][r] *= sr;
        }
      }
      float mnew = mi_[qf];
      float rsum = 0.0f;
      int row = (qf << 4) + l15;
#pragma unroll
      for (int nf = 0; nf < 4; nf++) {
        ushort4 pk;
        float p0 = __expf(s[qf][nf][0] - mnew);
        float p1 = __expf(s[qf][nf][1] - mnew);
        float p2 = __expf(s[qf][nf][2] - mnew);
        float p3 = __expf(s[qf][nf][3] - mnew);
        rsum += (p0 + p1) + (p2 + p3);
        pk.x = f2bf(p0); pk.y = f2bf(p1); pk.z = f2bf(p2); pk.w = f2bf(p3);
        int gs = ((nf << 2) + l4) ^ ((row & 7) << 1);
        *(ushort4*)&Ps[wave][row * 64 + gs * 4] = pk;
      }
      li_[qf] += rsum;  // lane-partial; reduced in epilogue
    }

    // PV: O[q][d] += P[q][k] * V[k][d]
    __builtin_amdgcn_s_setprio(1);
#pragma unroll
    for (int kk = 0; kk < 2; kk++) {
      bf16x8 pa[2];
#pragma unroll
      for (int qf = 0; qf < 2; qf++) {
        int row = (qf << 4) + l15;
        int gb = ((kk << 3) + (l4 << 1)) ^ ((row & 7) << 1);
        pa[qf] = *(const bf16x8*)&Ps[wave][row * 64 + gb * 4];
      }
      int slot = (kk << 2) + l4;
#pragma unroll
      for (int ni = 0; ni < 5; ni++) {
        int d = (ni << 4) + l15;
        bf16x8 bv = *(const bf16x8*)&Vb[d * 64 + ((slot ^ (d & 7)) << 3)];
        acc[0][ni] = __builtin_amdgcn_mfma_f32_16x16x32_bf16(pa[0], bv, acc[0][ni], 0, 0, 0);
        acc[1][ni] = __builtin_amdgcn_mfma_f32_16x16x32_bf16(pa[1], bv, acc[1][ni], 0, 0, 0);
      }
    }
    __builtin_amdgcn_s_setprio(0);
  }

  // epilogue: finish row-sum reduce, normalize, store
#pragma unroll
  for (int qf = 0; qf < 2; qf++) {
    float li = li_[qf];
    li += __shfl_xor(li, 16);
    li += __shfl_xor(li, 32);
#pragma unroll
    for (int r = 0; r < 4; r++) {
      float inv = 1.0f / __shfl(li, (l4 << 2) + r);
      int q = q0 + (qf << 4) + (l4 << 2) + r;
#pragma unroll
      for (int ni = 0; ni < 5; ni++) {
        int d = (ni << 4) + l15;
        if (d < HD) AO[(size_t)q * HID + h * HD + d] = f2bf(acc[qf][ni][r] * inv);
      }
    }
  }
}

extern "C" void kernel_launch(void* const* d_in, const int* in_sizes, int n_in,
                              void* d_out, int out_size, void* d_ws, size_t ws_size,
                              hipStream_t stream) {
  const float* X = (const float*)d_in[0];
  const float* cosv = (const float*)d_in[1];
  const float* sinv = (const float*)d_in[2];
  const float* Wq = (const float*)d_in[3];
  const float* Wk = (const float*)d_in[4];
  const float* Wv = (const float*)d_in[5];
  const float* Wo = (const float*)d_in[6];
  const float* qsc = (const float*)d_in[7];
  const float* ksc = (const float*)d_in[8];
  float* out = (float*)d_out;

  uint8_t* ws = (uint8_t*)d_ws;
  u16* Xb  = (u16*)(ws);                 //  9,437,184 B  (4096x1152 bf16)
  u16* Wt  = (u16*)(ws + 9437184);       //  7,962,624 B  (3456x1152 bf16)
  u16* Wot = (u16*)(ws + 17399808);      //  2,654,208 B  (1152x1152 bf16)
  u16* C1  = (u16*)(ws + 20054016);      // 28,311,552 B  (4096x3456 bf16)
  u16* Qp  = (u16*)(ws + 48365568);      // 12,582,912 B  (16x4096x96 bf16)
  u16* Kp  = (u16*)(ws + 60948480);      // 16,777,216 B  (16x4096x128 bf16, padded)
  u16* Vt  = (u16*)(ws + 77725696);      // 10,485,760 B  (16x80x4096 bf16)
  u16* AO  = Xb;                         // reuse: Xb consumed by GEMM1 before attn writes

  cvt_x<<<4608, 256, 0, stream>>>(X, Xb, (SEQ * HID) / 4);
  transpose_w<<<dim3(36, 36, 4), 256, 0, stream>>>(Wq, Wk, Wv, Wo, Wt, Wot);
  gemm_bt<1><<<dim3(32, 27), 256, 0, stream>>>(Xb, Wt, (void*)C1, SEQ, 3456, HID);
  norm_rope<<<dim3(128, 16), 256, 0, stream>>>(C1, cosv, sinv, qsc, ksc, Qp, Kp, Vt);
  attn<<<dim3(32, 16), 256, 0, stream>>>(Qp, Kp, Vt, AO);
  gemm_bt<0><<<dim3(32, 9), 256, 0, stream>>>(AO, Wot, (void*)out, SEQ, HID, HID);
}